// Round 4
// baseline (1825.090 us; speedup 1.0000x reference)
//
#include <hip/hip_runtime.h>
#include <hip/hip_bf16.h>
#include <cstdint>
#include <cstddef>

// Causal self-attention, B=2 S=2048 E=1024 H=16 D=64.
// Device inputs: fp32. Device OUTPUT: fp32 (reference returns float32; the
// "(bf16" in the harness assert label is hard-coded, threshold = 2% of
// max|ref|). Intermediates in ws: bf16.
// Round 3: final GEMM writes float to d_out. Rest identical to round 2.

#define B_  2
#define S_  2048
#define E_  1024
#define NH_ 16
#define DH_ 64
#define M_  (B_*S_)      // 4096
#define F_  (NH_*DH_)    // 1024

typedef unsigned short u16;

__device__ __forceinline__ float bf2f(u16 u) {
    union { unsigned int i; float f; } c; c.i = ((unsigned int)u) << 16; return c.f;
}
__device__ __forceinline__ u16 f2bf(float f) {
    union { float f; unsigned int i; } c; c.f = f;
    unsigned int x = c.i;
    x += 0x7fffu + ((x >> 16) & 1u);   // round-to-nearest-even
    return (u16)(x >> 16);
}

// ---------------------------------------------------------------------------
// GEMM: C[4096,1024] = A[4096,1024] @ W[1024,1024]; fp32 acc.
// MODE 0: A fp32 (x), bf16 out scattered to [b][h][s][d]   (QKV projection)
// MODE 2: A bf16 gathered from [b][h][s][d], fp32 row-major (output projection)
// W always fp32. 64x64 tile, BK=16, 256 threads, 4x4 microtile.
// ---------------------------------------------------------------------------
template<int MODE>
__global__ __launch_bounds__(256)
void gemm64(const void* __restrict__ Araw, const float* __restrict__ W,
            void* __restrict__ OutRaw)
{
    __shared__ float As[64][17];   // [m][k], pad -> conflict-free column reads
    __shared__ float Bs[16][64];   // [k][n]

    const int tid = threadIdx.x;
    const int tx = tid & 15, ty = tid >> 4;
    const int bx = blockIdx.x;     // N/64 = 16
    const int by = blockIdx.y;     // M/64 = 64

    float acc[4][4];
    #pragma unroll
    for (int i = 0; i < 4; ++i)
        #pragma unroll
        for (int j = 0; j < 4; ++j) acc[i][j] = 0.f;

    const int sArow = tid >> 2;          // 0..63
    const int sAcol = (tid & 3) * 4;     // 0,4,8,12
    const int sBrow = tid >> 4;          // 0..15
    const int sBcol = (tid & 15) * 4;    // 0..60

    const int aRow = by*64 + sArow;      // global A row (b*S+s flattened)
    const float* bPtr = W + (size_t)sBrow * (size_t)F_ + bx*64 + sBcol;

    for (int k0 = 0; k0 < E_; k0 += 16) {
        __syncthreads();
        if (MODE == 0) {
            float4 u = *(const float4*)((const float*)Araw +
                          (size_t)aRow * (size_t)E_ + k0 + sAcol);
            As[sArow][sAcol+0] = u.x;
            As[sArow][sAcol+1] = u.y;
            As[sArow][sAcol+2] = u.z;
            As[sArow][sAcol+3] = u.w;
        } else {
            // A stored as [b][h][s][d] bf16; logical col k = h*64+d
            int k = k0 + sAcol;
            int bb = aRow >> 11, ss = aRow & (S_-1);
            int hh = k >> 6,     dd = k & 63;         // k..k+3 same h (dd%4==0)
            ushort4 u = *(const ushort4*)((const u16*)Araw +
                          (((size_t)bb*NH_ + hh)*S_ + ss)*DH_ + dd);
            As[sArow][sAcol+0] = bf2f(u.x);
            As[sArow][sAcol+1] = bf2f(u.y);
            As[sArow][sAcol+2] = bf2f(u.z);
            As[sArow][sAcol+3] = bf2f(u.w);
        }
        {
            float4 u = *(const float4*)(bPtr + (size_t)k0 * F_);
            Bs[sBrow][sBcol+0] = u.x;
            Bs[sBrow][sBcol+1] = u.y;
            Bs[sBrow][sBcol+2] = u.z;
            Bs[sBrow][sBcol+3] = u.w;
        }
        __syncthreads();
        #pragma unroll
        for (int kk = 0; kk < 16; ++kk) {
            float a0 = As[ty   ][kk], a1 = As[ty+16][kk],
                  a2 = As[ty+32][kk], a3 = As[ty+48][kk];
            float b0 = Bs[kk][tx   ], b1 = Bs[kk][tx+16],
                  b2 = Bs[kk][tx+32], b3 = Bs[kk][tx+48];
            acc[0][0] += a0*b0; acc[0][1] += a0*b1; acc[0][2] += a0*b2; acc[0][3] += a0*b3;
            acc[1][0] += a1*b0; acc[1][1] += a1*b1; acc[1][2] += a1*b2; acc[1][3] += a1*b3;
            acc[2][0] += a2*b0; acc[2][1] += a2*b1; acc[2][2] += a2*b2; acc[2][3] += a2*b3;
            acc[3][0] += a3*b0; acc[3][1] += a3*b1; acc[3][2] += a3*b2; acc[3][3] += a3*b3;
        }
    }

    #pragma unroll
    for (int i = 0; i < 4; ++i) {
        int row = by*64 + ty + 16*i;
        #pragma unroll
        for (int j = 0; j < 4; ++j) {
            int col = bx*64 + tx + 16*j;
            if (MODE == 0) {
                int bb = row >> 11, ss = row & (S_-1);
                int hh = col >> 6,  dd = col & 63;
                ((u16*)OutRaw)[(((size_t)bb*NH_ + hh)*S_ + ss)*DH_ + dd] =
                    f2bf(acc[i][j]);
            } else {
                ((float*)OutRaw)[(size_t)row * F_ + col] = acc[i][j];
            }
        }
    }
}

// ---------------------------------------------------------------------------
// Flash-style causal attention. Q,K,V: [B][H][S][D] bf16 (ws).
// O overwrites this block's own Q tile bytes (sole reader+writer => race-free).
// ---------------------------------------------------------------------------
__global__ __launch_bounds__(256)
void attn64(const u16* Q, const u16* __restrict__ K,
            const u16* __restrict__ V, u16* O)
{
    __shared__ float qT[64][64];          // [d][local q]; reads wave-uniform
    __shared__ u16   kt_lds[64][68];      // +4 pad
    __shared__ u16   vt_lds[64][68];
    __shared__ float p_lds[4][64][18];    // per-wave [k][qi]

    const int tid  = threadIdx.x;
    const int lane = tid & 63;
    const int w    = tid >> 6;            // wave 0..3
    const int blk  = blockIdx.x;
    const int qg   = blk & 31;            // S/64 groups
    const int bh   = blk >> 5;            // b*NH+h
    const int q0   = qg * 64;

    const u16* Qb = Q + ((size_t)bh * S_ + q0) * DH_;
    const u16* Kb = K + (size_t)bh * S_ * DH_;
    const u16* Vb = V + (size_t)bh * S_ * DH_;

    {
        int row = tid >> 2;
        int seg = (tid & 3) * 16;
        const ushort4* src = (const ushort4*)(Qb + (size_t)row * DH_ + seg);
        #pragma unroll
        for (int t = 0; t < 4; ++t) {
            ushort4 u = src[t];
            qT[seg + t*4 + 0][row] = bf2f(u.x);
            qT[seg + t*4 + 1][row] = bf2f(u.y);
            qT[seg + t*4 + 2][row] = bf2f(u.z);
            qT[seg + t*4 + 3][row] = bf2f(u.w);
        }
    }

    float m[16], l[16], o[16];
    #pragma unroll
    for (int qi = 0; qi < 16; ++qi) { m[qi] = -1e30f; l[qi] = 0.f; o[qi] = 0.f; }

    const float scale = 0.125f;           // 1/sqrt(64)
    const int ntiles = qg + 1;

    for (int kt = 0; kt < ntiles; ++kt) {
        __syncthreads();
        {
            int row = tid >> 2;
            int seg = (tid & 3) * 16;
            const ushort4* ks = (const ushort4*)(Kb + (size_t)(kt*64 + row) * DH_ + seg);
            const ushort4* vs = (const ushort4*)(Vb + (size_t)(kt*64 + row) * DH_ + seg);
            #pragma unroll
            for (int t = 0; t < 4; ++t) {
                *(ushort4*)&kt_lds[row][seg + t*4] = ks[t];
                *(ushort4*)&vt_lds[row][seg + t*4] = vs[t];
            }
        }
        __syncthreads();

        float kreg[64];
        {
            const ushort4* kr = (const ushort4*)&kt_lds[lane][0];
            #pragma unroll
            for (int t = 0; t < 16; ++t) {
                ushort4 u = kr[t];
                kreg[t*4+0] = bf2f(u.x); kreg[t*4+1] = bf2f(u.y);
                kreg[t*4+2] = bf2f(u.z); kreg[t*4+3] = bf2f(u.w);
            }
        }

        float s[16];
        #pragma unroll
        for (int qi = 0; qi < 16; ++qi) s[qi] = 0.f;
        #pragma unroll
        for (int d = 0; d < 64; ++d) {
            float kd = kreg[d];
            const float4* qv = (const float4*)&qT[d][w*16];
            float4 a = qv[0], bq = qv[1], cq = qv[2], dq = qv[3];
            s[ 0] += kd*a.x;  s[ 1] += kd*a.y;  s[ 2] += kd*a.z;  s[ 3] += kd*a.w;
            s[ 4] += kd*bq.x; s[ 5] += kd*bq.y; s[ 6] += kd*bq.z; s[ 7] += kd*bq.w;
            s[ 8] += kd*cq.x; s[ 9] += kd*cq.y; s[10] += kd*cq.z; s[11] += kd*cq.w;
            s[12] += kd*dq.x; s[13] += kd*dq.y; s[14] += kd*dq.z; s[15] += kd*dq.w;
        }

        const int kglob = kt*64 + lane;
        #pragma unroll
        for (int qi = 0; qi < 16; ++qi) {
            int qglob = q0 + w*16 + qi;
            float sv = (kglob <= qglob) ? s[qi] * scale : -1e30f;
            float tm = sv;
            #pragma unroll
            for (int off = 32; off; off >>= 1) tm = fmaxf(tm, __shfl_xor(tm, off));
            float mn = fmaxf(m[qi], tm);
            float r  = __expf(m[qi] - mn);
            float p  = __expf(sv - mn);
            float ts = p;
            #pragma unroll
            for (int off = 32; off; off >>= 1) ts += __shfl_xor(ts, off);
            l[qi] = l[qi] * r + ts;
            o[qi] *= r;
            m[qi] = mn;
            p_lds[w][lane][qi] = p;
        }

        #pragma unroll 8
        for (int j = 0; j < 64; ++j) {
            float vj = bf2f(vt_lds[j][lane]);
            const float2* pv = (const float2*)&p_lds[w][j][0];
            #pragma unroll
            for (int t = 0; t < 8; ++t) {
                float2 pp = pv[t];
                o[2*t+0] += pp.x * vj;
                o[2*t+1] += pp.y * vj;
            }
        }
    }

    // write O into this block's own Q bytes, layout [b][h][s][d]
    #pragma unroll
    for (int qi = 0; qi < 16; ++qi) {
        int qglob = q0 + w*16 + qi;
        float val = o[qi] / l[qi];
        O[((size_t)bh * S_ + qglob) * DH_ + lane] = f2bf(val);
    }
}

// ---------------------------------------------------------------------------
extern "C" void kernel_launch(void* const* d_in, const int* in_sizes, int n_in,
                              void* d_out, int out_size, void* d_ws, size_t ws_size,
                              hipStream_t stream) {
    (void)in_sizes; (void)n_in; (void)out_size; (void)ws_size;
    const float* x  = (const float*)d_in[0];
    const float* wq = (const float*)d_in[1];
    const float* wk = (const float*)d_in[2];
    const float* wv = (const float*)d_in[3];
    const float* wo = (const float*)d_in[4];

    u16* Qw = (u16*)d_ws;                    // [B][H][S][D] bf16, 8 MiB (O reuses)
    u16* Kw = Qw + (size_t)M_ * F_;          // 8 MiB
    u16* Vw = Kw + (size_t)M_ * F_;          // 8 MiB  -> total 24 MiB
    dim3 g(F_/64, M_/64), blk(256);
    gemm64<0><<<g, blk, 0, stream>>>((const void*)x, wq, (void*)Qw);
    gemm64<0><<<g, blk, 0, stream>>>((const void*)x, wk, (void*)Kw);
    gemm64<0><<<g, blk, 0, stream>>>((const void*)x, wv, (void*)Vw);
    attn64<<<dim3(B_*NH_*(S_/64)), blk, 0, stream>>>(Qw, Kw, Vw, Qw);
    gemm64<2><<<g, blk, 0, stream>>>((const void*)Qw, wo, d_out);
}

// Round 5
// 732.862 us; speedup vs baseline: 2.4904x; 2.4904x over previous
//
#include <hip/hip_runtime.h>
#include <hip/hip_bf16.h>
#include <cstdint>
#include <cstddef>

// Causal self-attention, B=2 S=2048 E=1024 H=16 D=64.
// Inputs fp32, output fp32, ws intermediates bf16.
// Round 4: MFMA flash attention (16x16x32 bf16). GEMMs unchanged.

#define B_  2
#define S_  2048
#define E_  1024
#define NH_ 16
#define DH_ 64
#define M_  (B_*S_)      // 4096
#define F_  (NH_*DH_)    // 1024

typedef unsigned short u16;
typedef short short8 __attribute__((ext_vector_type(8)));
typedef float f32x4  __attribute__((ext_vector_type(4)));

__device__ __forceinline__ float bf2f(u16 u) {
    union { unsigned int i; float f; } c; c.i = ((unsigned int)u) << 16; return c.f;
}
__device__ __forceinline__ u16 f2bf(float f) {
    union { float f; unsigned int i; } c; c.f = f;
    unsigned int x = c.i;
    x += 0x7fffu + ((x >> 16) & 1u);   // RNE
    return (u16)(x >> 16);
}

// ---------------------------------------------------------------------------
// GEMM (unchanged from round 3): C = A @ W, fp32 acc.
// MODE 0: A fp32 (x), bf16 out scattered to [b][h][s][d]
// MODE 2: A bf16 gathered from [b][h][s][d], fp32 row-major out
// ---------------------------------------------------------------------------
template<int MODE>
__global__ __launch_bounds__(256)
void gemm64(const void* __restrict__ Araw, const float* __restrict__ W,
            void* __restrict__ OutRaw)
{
    __shared__ float As[64][17];
    __shared__ float Bs[16][64];

    const int tid = threadIdx.x;
    const int tx = tid & 15, ty = tid >> 4;
    const int bx = blockIdx.x;
    const int by = blockIdx.y;

    float acc[4][4];
    #pragma unroll
    for (int i = 0; i < 4; ++i)
        #pragma unroll
        for (int j = 0; j < 4; ++j) acc[i][j] = 0.f;

    const int sArow = tid >> 2;
    const int sAcol = (tid & 3) * 4;
    const int sBrow = tid >> 4;
    const int sBcol = (tid & 15) * 4;

    const int aRow = by*64 + sArow;
    const float* bPtr = W + (size_t)sBrow * (size_t)F_ + bx*64 + sBcol;

    for (int k0 = 0; k0 < E_; k0 += 16) {
        __syncthreads();
        if (MODE == 0) {
            float4 u = *(const float4*)((const float*)Araw +
                          (size_t)aRow * (size_t)E_ + k0 + sAcol);
            As[sArow][sAcol+0] = u.x;
            As[sArow][sAcol+1] = u.y;
            As[sArow][sAcol+2] = u.z;
            As[sArow][sAcol+3] = u.w;
        } else {
            int k = k0 + sAcol;
            int bb = aRow >> 11, ss = aRow & (S_-1);
            int hh = k >> 6,     dd = k & 63;
            ushort4 u = *(const ushort4*)((const u16*)Araw +
                          (((size_t)bb*NH_ + hh)*S_ + ss)*DH_ + dd);
            As[sArow][sAcol+0] = bf2f(u.x);
            As[sArow][sAcol+1] = bf2f(u.y);
            As[sArow][sAcol+2] = bf2f(u.z);
            As[sArow][sAcol+3] = bf2f(u.w);
        }
        {
            float4 u = *(const float4*)(bPtr + (size_t)k0 * F_);
            Bs[sBrow][sBcol+0] = u.x;
            Bs[sBrow][sBcol+1] = u.y;
            Bs[sBrow][sBcol+2] = u.z;
            Bs[sBrow][sBcol+3] = u.w;
        }
        __syncthreads();
        #pragma unroll
        for (int kk = 0; kk < 16; ++kk) {
            float a0 = As[ty   ][kk], a1 = As[ty+16][kk],
                  a2 = As[ty+32][kk], a3 = As[ty+48][kk];
            float b0 = Bs[kk][tx   ], b1 = Bs[kk][tx+16],
                  b2 = Bs[kk][tx+32], b3 = Bs[kk][tx+48];
            acc[0][0] += a0*b0; acc[0][1] += a0*b1; acc[0][2] += a0*b2; acc[0][3] += a0*b3;
            acc[1][0] += a1*b0; acc[1][1] += a1*b1; acc[1][2] += a1*b2; acc[1][3] += a1*b3;
            acc[2][0] += a2*b0; acc[2][1] += a2*b1; acc[2][2] += a2*b2; acc[2][3] += a2*b3;
            acc[3][0] += a3*b0; acc[3][1] += a3*b1; acc[3][2] += a3*b2; acc[3][3] += a3*b3;
        }
    }

    #pragma unroll
    for (int i = 0; i < 4; ++i) {
        int row = by*64 + ty + 16*i;
        #pragma unroll
        for (int j = 0; j < 4; ++j) {
            int col = bx*64 + tx + 16*j;
            if (MODE == 0) {
                int bb = row >> 11, ss = row & (S_-1);
                int hh = col >> 6,  dd = col & 63;
                ((u16*)OutRaw)[(((size_t)bb*NH_ + hh)*S_ + ss)*DH_ + dd] =
                    f2bf(acc[i][j]);
            } else {
                ((float*)OutRaw)[(size_t)row * F_ + col] = acc[i][j];
            }
        }
    }
}

// ---------------------------------------------------------------------------
// MFMA flash attention. Q,K,V: [B][H][S][D] bf16 (ws). O overwrites own Q tile.
// Block = (b,h) x 64 q rows; 4 waves x 16 q rows. KV tiles of 64.
// S^T = mfma(A=K, B=Q^T): D[key'][q'], key' = 4*(lane>>4)+reg, q' = lane&15.
// P -> bf16 -> per-wave LDS [q][key] (XOR swizzle) -> A-frag for PV = mfma(P,V).
// V staged transposed in LDS [d][key] (row-XOR swizzle) -> B-frags ds_read_b128.
// ---------------------------------------------------------------------------
__global__ __launch_bounds__(256)
void attn_mfma(const u16* Q, const u16* __restrict__ K,
               const u16* __restrict__ V, u16* O)
{
    __shared__ u16 vt[64*64];       // V^T [d][key], 8 KB, swizzled
    __shared__ u16 pl[4][16*64];    // per-wave P [q][key], 8 KB total, swizzled

    const int tid  = threadIdx.x;
    const int lane = tid & 63;
    const int w    = tid >> 6;
    const int g    = lane >> 4;     // 4-lane-group 0..3
    const int q15  = lane & 15;

    const int blk = blockIdx.x;
    const int tq  = blk & 31;
    const int qg  = (tq & 1) ? (31 - (tq >> 1)) : (tq >> 1);  // heavy/light pairing
    const int bh  = blk >> 5;
    const int q0  = qg * 64;

    const u16* Kb = K + (size_t)bh * S_ * DH_;
    const u16* Vb = V + (size_t)bh * S_ * DH_;

    // Q fragments (B-operand of S^T): lane holds Q[q0+w*16+q15][8g+j (+32)]
    short8 qf0, qf1;
    {
        const u16* Qp = Q + ((size_t)bh * S_ + q0 + w*16 + q15) * DH_ + g*8;
        qf0 = *(const short8*)(Qp);
        qf1 = *(const short8*)(Qp + 32);
    }

    f32x4 o[4];
    #pragma unroll
    for (int dt = 0; dt < 4; ++dt) o[dt] = (f32x4){0.f,0.f,0.f,0.f};
    float mrow = -1e30f, lrow = 0.f;

    for (int kt = 0; kt <= qg; ++kt) {
        __syncthreads();                    // vt consumers (prev iter) done
        // ---- stage V^T[d][key] with transpose-on-write ----
        {
            int key = tid >> 2;
            int d0  = (tid & 3) * 16;
            const u16* vs = Vb + (size_t)(kt*64 + key) * DH_ + d0;
            short8 v0 = *(const short8*)(vs);
            short8 v1 = *(const short8*)(vs + 8);
            #pragma unroll
            for (int j = 0; j < 8; ++j) {
                int d = d0 + j;
                vt[(d*128 + ((key*2) ^ ((d&7)<<4))) >> 1] = ((const u16*)&v0)[j];
            }
            #pragma unroll
            for (int j = 0; j < 8; ++j) {
                int d = d0 + 8 + j;
                vt[(d*128 + ((key*2) ^ ((d&7)<<4))) >> 1] = ((const u16*)&v1)[j];
            }
        }
        __syncthreads();                    // vt ready

        // ---- S^T tiles: 4 x (16 keys x 16 q), K frags direct from global ----
        float p[16];
        {
            const u16* Kp = Kb + (size_t)(kt*64 + q15) * DH_ + g*8;
            #pragma unroll
            for (int t = 0; t < 4; ++t) {
                f32x4 st = (f32x4){0.f,0.f,0.f,0.f};
                short8 kf0 = *(const short8*)(Kp + (size_t)t*16*DH_);
                short8 kf1 = *(const short8*)(Kp + (size_t)t*16*DH_ + 32);
                st = __builtin_amdgcn_mfma_f32_16x16x32_bf16(kf0, qf0, st, 0, 0, 0);
                st = __builtin_amdgcn_mfma_f32_16x16x32_bf16(kf1, qf1, st, 0, 0, 0);
                #pragma unroll
                for (int r = 0; r < 4; ++r) p[t*4+r] = st[r] * 0.125f;
            }
        }

        // causal mask (only diagonal KV tile), key' = 16t+4g+r vs q' = w*16+q15
        if (kt == qg) {
            #pragma unroll
            for (int t = 0; t < 4; ++t)
                #pragma unroll
                for (int r = 0; r < 4; ++r)
                    if (16*t + 4*g + r > w*16 + q15) p[t*4+r] = -1e30f;
        }

        // ---- online softmax (row = q15, spread over lane groups) ----
        float tmax = p[0];
        #pragma unroll
        for (int i = 1; i < 16; ++i) tmax = fmaxf(tmax, p[i]);
        tmax = fmaxf(tmax, __shfl_xor(tmax, 16));
        tmax = fmaxf(tmax, __shfl_xor(tmax, 32));
        float mnew = fmaxf(mrow, tmax);
        float rsc  = __expf(mrow - mnew);
        mrow = mnew;
        float psum = 0.f;
        #pragma unroll
        for (int i = 0; i < 16; ++i) { p[i] = __expf(p[i] - mnew); psum += p[i]; }
        psum += __shfl_xor(psum, 16);
        psum += __shfl_xor(psum, 32);
        lrow = lrow * rsc + psum;

        // rescale O: lane's O rows are q' = 4g+r -> fetch factors from lane 4g+r
        #pragma unroll
        for (int r = 0; r < 4; ++r) {
            float rr = __shfl(rsc, 4*g + r);
            #pragma unroll
            for (int dt = 0; dt < 4; ++dt) o[dt][r] *= rr;
        }

        // ---- P -> bf16 -> per-wave LDS [q=q15][key=16t+4g+r], swizzled ----
        char* plw = (char*)&pl[w][0];
        #pragma unroll
        for (int t = 0; t < 4; ++t) {
            ushort4 pw;
            pw.x = f2bf(p[t*4+0]); pw.y = f2bf(p[t*4+1]);
            pw.z = f2bf(p[t*4+2]); pw.w = f2bf(p[t*4+3]);
            int byte = q15*128 + ((32*t + 8*g) ^ ((q15&7)<<4));
            *(ushort4*)(plw + byte) = pw;
        }

        // ---- PV: 2 key-chunks x 4 d-tiles ----
        #pragma unroll
        for (int c = 0; c < 2; ++c) {
            int pb = q15*128 + ((64*c + 16*g) ^ ((q15&7)<<4));
            short8 pf = *(const short8*)(plw + pb);
            #pragma unroll
            for (int dt = 0; dt < 4; ++dt) {
                int d = dt*16 + q15;
                int vb = d*128 + ((64*c + 16*g) ^ ((d&7)<<4));
                short8 vf = *(const short8*)((char*)vt + vb);
                o[dt] = __builtin_amdgcn_mfma_f32_16x16x32_bf16(pf, vf, o[dt], 0, 0, 0);
            }
        }
    }

    // ---- epilogue: divide by l, write O into own Q bytes [b][h][s][d] ----
    float inv = 1.f / lrow;
    #pragma unroll
    for (int r = 0; r < 4; ++r) {
        float li = __shfl(inv, 4*g + r);
        int qrow = q0 + w*16 + 4*g + r;
        #pragma unroll
        for (int dt = 0; dt < 4; ++dt) {
            O[((size_t)bh * S_ + qrow) * DH_ + dt*16 + q15] = f2bf(o[dt][r] * li);
        }
    }
}

// ---------------------------------------------------------------------------
extern "C" void kernel_launch(void* const* d_in, const int* in_sizes, int n_in,
                              void* d_out, int out_size, void* d_ws, size_t ws_size,
                              hipStream_t stream) {
    (void)in_sizes; (void)n_in; (void)out_size; (void)ws_size;
    const float* x  = (const float*)d_in[0];
    const float* wq = (const float*)d_in[1];
    const float* wk = (const float*)d_in[2];
    const float* wv = (const float*)d_in[3];
    const float* wo = (const float*)d_in[4];

    u16* Qw = (u16*)d_ws;                    // [B][H][S][D] bf16 (O reuses)
    u16* Kw = Qw + (size_t)M_ * F_;
    u16* Vw = Kw + (size_t)M_ * F_;
    dim3 g(F_/64, M_/64), blk(256);
    gemm64<0><<<g, blk, 0, stream>>>((const void*)x, wq, (void*)Qw);
    gemm64<0><<<g, blk, 0, stream>>>((const void*)x, wk, (void*)Kw);
    gemm64<0><<<g, blk, 0, stream>>>((const void*)x, wv, (void*)Vw);
    attn_mfma<<<dim3(B_*NH_*(S_/64)), blk, 0, stream>>>(Qw, Kw, Vw, Qw);
    gemm64<2><<<g, blk, 0, stream>>>((const void*)Qw, wo, d_out);
}

// Round 6
// 245.735 us; speedup vs baseline: 7.4271x; 2.9823x over previous
//
#include <hip/hip_runtime.h>
#include <hip/hip_bf16.h>
#include <cstdint>
#include <cstddef>

// Causal self-attention, B=2 S=2048 E=1024 H=16 D=64.
// Inputs fp32, output fp32, ws intermediates bf16.
// Round 5: MFMA GEMMs (16x16x32 bf16), QKV fused (grid.z=3), reg-staged
// fp32->bf16 conversion, T2 XOR-swizzled LDS, global prefetch under MFMA.
// Attention kernel unchanged from round 4 (verified, ~21 us).

#define B_  2
#define S_  2048
#define E_  1024
#define NH_ 16
#define DH_ 64
#define M_  (B_*S_)      // 4096
#define F_  (NH_*DH_)    // 1024

typedef unsigned short u16;
typedef short short8 __attribute__((ext_vector_type(8)));
typedef float f32x4  __attribute__((ext_vector_type(4)));

__device__ __forceinline__ float bf2f(u16 u) {
    union { unsigned int i; float f; } c; c.i = ((unsigned int)u) << 16; return c.f;
}
__device__ __forceinline__ u16 f2bf(float f) {
    union { float f; unsigned int i; } c; c.f = f;
    unsigned int x = c.i;
    x += 0x7fffu + ((x >> 16) & 1u);   // RNE
    return (u16)(x >> 16);
}

// ---------------------------------------------------------------------------
// MFMA GEMM, 128x128 tile, BK=64, 4 waves (2x2 of 64x64), fp32 acc.
// MODE 0: A = x fp32 [M][E]; W fp32; out bf16 scattered to [b][h][s][d].
//         grid.z selects (W, Out) among q/k/v.
// MODE 2: A = attn-O bf16 [b][h][s][d] (gather); W fp32; out fp32 row-major.
// LDS: A [row128][k64] bf16, B [n128][k64] bf16, both byte^=((row&7)<<4).
// ---------------------------------------------------------------------------
template<int MODE>
__global__ __launch_bounds__(256)
void mfma_gemm(const void* __restrict__ Araw,
               const float* __restrict__ W0, const float* __restrict__ W1,
               const float* __restrict__ W2,
               void* __restrict__ Out0, void* __restrict__ Out1,
               void* __restrict__ Out2)
{
    __shared__ __align__(16) char lds[32768];
    char* lA = lds;            // 128 rows * 128 B
    char* lB = lds + 16384;    // 128 n    * 128 B

    const int tid = threadIdx.x;
    const int lane = tid & 63;
    const int w    = tid >> 6;
    const int wr   = w >> 1, wc = w & 1;
    const int g    = lane >> 4;
    const int q15  = lane & 15;
    const int bx   = blockIdx.x;       // N/128 = 8
    const int by   = blockIdx.y;       // M/128 = 32
    const int z    = (MODE == 0) ? blockIdx.z : 0;

    const float* W   = (z == 0) ? W0 : (z == 1) ? W1 : W2;
    void*        Out = (z == 0) ? Out0 : (z == 1) ? Out1 : Out2;

    // staging coords
    const int sArow = tid >> 1;            // 0..127
    const int sAseg = (tid & 1) * 32;      // 0,32
    const int sBkb  = (tid >> 2) & 7;      // 0..7  (8 k rows)
    const int sBcb  = (tid >> 5) * 4 + (tid & 3);  // 0..31 (4 n cols)

    f32x4 acc[4][4];
    #pragma unroll
    for (int i = 0; i < 4; ++i)
        #pragma unroll
        for (int j = 0; j < 4; ++j) acc[i][j] = (f32x4){0.f,0.f,0.f,0.f};

    // prefetch registers
    float4 pa[8];            // MODE 0: 32 floats of x
    short8 pa2[4];           // MODE 2: 32 bf16 of O
    float4 pb[8];            // 8 k-rows x 4 n-cols of W

    const int aRow = by*128 + sArow;
    const int ab   = aRow >> 11, as = aRow & (S_-1);

    auto LOADA = [&](int k0) {
        if (MODE == 0) {
            const float* ap = (const float*)Araw + (size_t)aRow * E_ + k0 + sAseg;
            #pragma unroll
            for (int u = 0; u < 8; ++u) pa[u] = ((const float4*)ap)[u];
        } else {
            int h = k0 >> 6;
            const u16* ap = (const u16*)Araw +
                (((size_t)ab*NH_ + h)*S_ + as)*DH_ + sAseg;
            #pragma unroll
            for (int u = 0; u < 4; ++u) pa2[u] = ((const short8*)ap)[u];
        }
    };
    auto LOADB = [&](int k0) {
        const float* bp = W + (size_t)(k0 + sBkb*8) * F_ + bx*128 + sBcb*4;
        #pragma unroll
        for (int j = 0; j < 8; ++j) pb[j] = *(const float4*)(bp + (size_t)j * F_);
    };
    auto WRITEA = [&]() {
        #pragma unroll
        for (int c = 0; c < 4; ++c) {
            short8 ch;
            if (MODE == 0) {
                const float* f0 = (const float*)&pa[2*c];
                #pragma unroll
                for (int j = 0; j < 8; ++j) ((u16*)&ch)[j] = f2bf(f0[j]);
            } else ch = pa2[c];
            *(short8*)(lA + sArow*128 + ((sAseg*2 + 16*c) ^ ((sArow&7)<<4))) = ch;
        }
    };
    auto WRITEB = [&]() {
        #pragma unroll
        for (int c = 0; c < 4; ++c) {
            short8 bs;
            #pragma unroll
            for (int j = 0; j < 8; ++j)
                ((u16*)&bs)[j] = f2bf(((const float*)&pb[j])[c]);
            int n = sBcb*4 + c;
            *(short8*)(lB + n*128 + ((16*sBkb) ^ ((n&7)<<4))) = bs;
        }
    };

    LOADA(0); LOADB(0);

    for (int it = 0; it < E_/64; ++it) {
        __syncthreads();
        WRITEA(); WRITEB();
        __syncthreads();
        if (it + 1 < E_/64) { LOADA((it+1)*64); LOADB((it+1)*64); }
        #pragma unroll
        for (int s = 0; s < 2; ++s) {
            short8 af[4], bfr[4];
            #pragma unroll
            for (int mt = 0; mt < 4; ++mt) {
                int row = wr*64 + mt*16 + q15;
                af[mt] = *(const short8*)(lA + row*128 + ((s*64 + 16*g) ^ ((row&7)<<4)));
            }
            #pragma unroll
            for (int nt = 0; nt < 4; ++nt) {
                int n = wc*64 + nt*16 + q15;
                bfr[nt] = *(const short8*)(lB + n*128 + ((s*64 + 16*g) ^ ((n&7)<<4)));
            }
            #pragma unroll
            for (int mt = 0; mt < 4; ++mt)
                #pragma unroll
                for (int nt = 0; nt < 4; ++nt)
                    acc[mt][nt] = __builtin_amdgcn_mfma_f32_16x16x32_bf16(
                        af[mt], bfr[nt], acc[mt][nt], 0, 0, 0);
        }
    }

    // epilogue
    #pragma unroll
    for (int mt = 0; mt < 4; ++mt) {
        #pragma unroll
        for (int r = 0; r < 4; ++r) {
            int grow = by*128 + wr*64 + mt*16 + 4*g + r;
            if (MODE == 0) {
                int bb = grow >> 11, ss = grow & (S_-1);
                #pragma unroll
                for (int nt = 0; nt < 4; ++nt) {
                    int n = bx*128 + wc*64 + nt*16 + q15;
                    int hh = n >> 6, dd = n & 63;
                    ((u16*)Out)[(((size_t)bb*NH_ + hh)*S_ + ss)*DH_ + dd] =
                        f2bf(acc[mt][nt][r]);
                }
            } else {
                #pragma unroll
                for (int nt = 0; nt < 4; ++nt) {
                    int n = bx*128 + wc*64 + nt*16 + q15;
                    ((float*)Out)[(size_t)grow * F_ + n] = acc[mt][nt][r];
                }
            }
        }
    }
}

// ---------------------------------------------------------------------------
// MFMA flash attention (unchanged from round 4, verified).
// ---------------------------------------------------------------------------
__global__ __launch_bounds__(256)
void attn_mfma(const u16* Q, const u16* __restrict__ K,
               const u16* __restrict__ V, u16* O)
{
    __shared__ u16 vt[64*64];
    __shared__ u16 pl[4][16*64];

    const int tid  = threadIdx.x;
    const int lane = tid & 63;
    const int w    = tid >> 6;
    const int g    = lane >> 4;
    const int q15  = lane & 15;

    const int blk = blockIdx.x;
    const int tq  = blk & 31;
    const int qg  = (tq & 1) ? (31 - (tq >> 1)) : (tq >> 1);
    const int bh  = blk >> 5;
    const int q0  = qg * 64;

    const u16* Kb = K + (size_t)bh * S_ * DH_;
    const u16* Vb = V + (size_t)bh * S_ * DH_;

    short8 qf0, qf1;
    {
        const u16* Qp = Q + ((size_t)bh * S_ + q0 + w*16 + q15) * DH_ + g*8;
        qf0 = *(const short8*)(Qp);
        qf1 = *(const short8*)(Qp + 32);
    }

    f32x4 o[4];
    #pragma unroll
    for (int dt = 0; dt < 4; ++dt) o[dt] = (f32x4){0.f,0.f,0.f,0.f};
    float mrow = -1e30f, lrow = 0.f;

    for (int kt = 0; kt <= qg; ++kt) {
        __syncthreads();
        {
            int key = tid >> 2;
            int d0  = (tid & 3) * 16;
            const u16* vs = Vb + (size_t)(kt*64 + key) * DH_ + d0;
            short8 v0 = *(const short8*)(vs);
            short8 v1 = *(const short8*)(vs + 8);
            #pragma unroll
            for (int j = 0; j < 8; ++j) {
                int d = d0 + j;
                vt[(d*128 + ((key*2) ^ ((d&7)<<4))) >> 1] = ((const u16*)&v0)[j];
            }
            #pragma unroll
            for (int j = 0; j < 8; ++j) {
                int d = d0 + 8 + j;
                vt[(d*128 + ((key*2) ^ ((d&7)<<4))) >> 1] = ((const u16*)&v1)[j];
            }
        }
        __syncthreads();

        float p[16];
        {
            const u16* Kp = Kb + (size_t)(kt*64 + q15) * DH_ + g*8;
            #pragma unroll
            for (int t = 0; t < 4; ++t) {
                f32x4 st = (f32x4){0.f,0.f,0.f,0.f};
                short8 kf0 = *(const short8*)(Kp + (size_t)t*16*DH_);
                short8 kf1 = *(const short8*)(Kp + (size_t)t*16*DH_ + 32);
                st = __builtin_amdgcn_mfma_f32_16x16x32_bf16(kf0, qf0, st, 0, 0, 0);
                st = __builtin_amdgcn_mfma_f32_16x16x32_bf16(kf1, qf1, st, 0, 0, 0);
                #pragma unroll
                for (int r = 0; r < 4; ++r) p[t*4+r] = st[r] * 0.125f;
            }
        }

        if (kt == qg) {
            #pragma unroll
            for (int t = 0; t < 4; ++t)
                #pragma unroll
                for (int r = 0; r < 4; ++r)
                    if (16*t + 4*g + r > w*16 + q15) p[t*4+r] = -1e30f;
        }

        float tmax = p[0];
        #pragma unroll
        for (int i = 1; i < 16; ++i) tmax = fmaxf(tmax, p[i]);
        tmax = fmaxf(tmax, __shfl_xor(tmax, 16));
        tmax = fmaxf(tmax, __shfl_xor(tmax, 32));
        float mnew = fmaxf(mrow, tmax);
        float rsc  = __expf(mrow - mnew);
        mrow = mnew;
        float psum = 0.f;
        #pragma unroll
        for (int i = 0; i < 16; ++i) { p[i] = __expf(p[i] - mnew); psum += p[i]; }
        psum += __shfl_xor(psum, 16);
        psum += __shfl_xor(psum, 32);
        lrow = lrow * rsc + psum;

        #pragma unroll
        for (int r = 0; r < 4; ++r) {
            float rr = __shfl(rsc, 4*g + r);
            #pragma unroll
            for (int dt = 0; dt < 4; ++dt) o[dt][r] *= rr;
        }

        char* plw = (char*)&pl[w][0];
        #pragma unroll
        for (int t = 0; t < 4; ++t) {
            ushort4 pw;
            pw.x = f2bf(p[t*4+0]); pw.y = f2bf(p[t*4+1]);
            pw.z = f2bf(p[t*4+2]); pw.w = f2bf(p[t*4+3]);
            int byte = q15*128 + ((32*t + 8*g) ^ ((q15&7)<<4));
            *(ushort4*)(plw + byte) = pw;
        }

        #pragma unroll
        for (int c = 0; c < 2; ++c) {
            int pb = q15*128 + ((64*c + 16*g) ^ ((q15&7)<<4));
            short8 pf = *(const short8*)(plw + pb);
            #pragma unroll
            for (int dt = 0; dt < 4; ++dt) {
                int d = dt*16 + q15;
                int vb = d*128 + ((64*c + 16*g) ^ ((d&7)<<4));
                short8 vf = *(const short8*)((char*)vt + vb);
                o[dt] = __builtin_amdgcn_mfma_f32_16x16x32_bf16(pf, vf, o[dt], 0, 0, 0);
            }
        }
    }

    float inv = 1.f / lrow;
    #pragma unroll
    for (int r = 0; r < 4; ++r) {
        float li = __shfl(inv, 4*g + r);
        int qrow = q0 + w*16 + 4*g + r;
        #pragma unroll
        for (int dt = 0; dt < 4; ++dt) {
            O[((size_t)bh * S_ + qrow) * DH_ + dt*16 + q15] = f2bf(o[dt][r] * li);
        }
    }
}

// ---------------------------------------------------------------------------
extern "C" void kernel_launch(void* const* d_in, const int* in_sizes, int n_in,
                              void* d_out, int out_size, void* d_ws, size_t ws_size,
                              hipStream_t stream) {
    (void)in_sizes; (void)n_in; (void)out_size; (void)ws_size;
    const float* x  = (const float*)d_in[0];
    const float* wq = (const float*)d_in[1];
    const float* wk = (const float*)d_in[2];
    const float* wv = (const float*)d_in[3];
    const float* wo = (const float*)d_in[4];

    u16* Qw = (u16*)d_ws;                    // [B][H][S][D] bf16 (O reuses)
    u16* Kw = Qw + (size_t)M_ * F_;
    u16* Vw = Kw + (size_t)M_ * F_;          // total 24 MiB

    mfma_gemm<0><<<dim3(F_/128, M_/128, 3), 256, 0, stream>>>(
        (const void*)x, wq, wk, wv, (void*)Qw, (void*)Kw, (void*)Vw);
    attn_mfma<<<dim3(B_*NH_*(S_/64)), 256, 0, stream>>>(Qw, Kw, Vw, Qw);
    mfma_gemm<2><<<dim3(F_/128, M_/128, 1), 256, 0, stream>>>(
        (const void*)Qw, wo, wo, wo, d_out, d_out, d_out);
}